// Round 3
// baseline (3004.608 us; speedup 1.0000x reference)
//
#include <hip/hip_runtime.h>
#include <hip/hip_bf16.h>
#include <math.h>

typedef float f4 __attribute__((ext_vector_type(4)));
typedef _Float16 h8 __attribute__((ext_vector_type(8)));
typedef float f32x4 __attribute__((ext_vector_type(4)));

#define NB 8
#define NS 785
#define ND 128
#define NH 8
#define NDH 64
#define NDF 512
#define NL 6
#define NP 784
#define NCIN 512
#define NM (NB*NS)   // 6280

// ---------------------------------------------------------------- conv stem
__global__ __launch_bounds__(256) void conv_bn_relu_kernel(
    const float* __restrict__ x, const float* __restrict__ w,
    const float* __restrict__ gamma, const float* __restrict__ beta,
    const float* __restrict__ mean, const float* __restrict__ var,
    float* __restrict__ enc, unsigned int* __restrict__ maxv)
{
    __shared__ float xt[64][17];    // [c][p]
    __shared__ float wt[64][132];   // [c][d]
    __shared__ float red[4];
    const int b  = blockIdx.y;
    const int p0 = blockIdx.x * 16;       // 49*16 = 784 exact
    const int t  = threadIdx.x;
    const int pl = (t & 3) * 4;           // 4 pixels
    const int dl = (t >> 2) * 2;          // 2 channels
    float acc[2][4] = {};
    for (int c0 = 0; c0 < NCIN; c0 += 64) {
        __syncthreads();
        {
            int cc = t >> 2, pp = (t & 3) * 4;
            f4 v = *(const f4*)&x[(size_t)(b*NCIN + c0 + cc)*NP + p0 + pp];
            xt[cc][pp+0] = v[0]; xt[cc][pp+1] = v[1]; xt[cc][pp+2] = v[2]; xt[cc][pp+3] = v[3];
        }
        #pragma unroll
        for (int i = 0; i < 8; i++) {
            int e = t + i*256;
            int d = e >> 4, c4 = (e & 15) * 4;
            f4 v = *(const f4*)&w[(size_t)d*NCIN + c0 + c4];
            wt[c4+0][d] = v[0]; wt[c4+1][d] = v[1]; wt[c4+2][d] = v[2]; wt[c4+3][d] = v[3];
        }
        __syncthreads();
        #pragma unroll 8
        for (int cc = 0; cc < 64; cc++) {
            float w0 = wt[cc][dl], w1 = wt[cc][dl+1];
            float x0 = xt[cc][pl+0], x1 = xt[cc][pl+1], x2 = xt[cc][pl+2], x3 = xt[cc][pl+3];
            acc[0][0] += w0*x0; acc[0][1] += w0*x1; acc[0][2] += w0*x2; acc[0][3] += w0*x3;
            acc[1][0] += w1*x0; acc[1][1] += w1*x1; acc[1][2] += w1*x2; acc[1][3] += w1*x3;
        }
    }
    float lmax = 0.f;
    #pragma unroll
    for (int i = 0; i < 2; i++) {
        int d = dl + i;
        float inv = rsqrtf(var[d] + 1e-5f);
        float sc = gamma[d] * inv;
        float sh = beta[d] - mean[d] * sc;
        #pragma unroll
        for (int j = 0; j < 4; j++) {
            float vo = fmaxf(acc[i][j]*sc + sh, 0.f);
            lmax = fmaxf(lmax, vo);
            enc[(size_t)(b*NP + p0 + pl + j)*ND + d] = vo;
        }
    }
    for (int o = 1; o < 64; o <<= 1) lmax = fmaxf(lmax, __shfl_xor(lmax, o));
    if ((t & 63) == 0) red[t >> 6] = lmax;
    __syncthreads();
    if (t == 0) {
        float m2 = fmaxf(fmaxf(red[0], red[1]), fmaxf(red[2], red[3]));
        atomicMax(maxv, __float_as_uint(m2));
    }
}

// ---------------------------------------------------------------- assemble xs/xf
__global__ void assemble_kernel(
    const float* __restrict__ encx, const float* __restrict__ ency,
    const float* __restrict__ cls, const float* __restrict__ pos,
    const float* __restrict__ maxv, float* __restrict__ xs, float* __restrict__ xf)
{
    int i = blockIdx.x*256 + threadIdx.x;   // < 8*785*128 = 803840 exact
    int d = i & 127;
    int s = (i >> 7) % NS;
    int b = i / (NS*ND);
    float inv = 1.f / maxv[0];
    float pv = pos[s*ND + d];
    float xv, yv;
    if (s == 0) { xv = cls[d]; yv = cls[d]; }
    else {
        int idx = (b*NP + s - 1)*ND + d;
        xv = encx[idx]*inv; yv = ency[idx]*inv;
    }
    xs[i] = xv + pv;
    xf[i] = yv + pv;
}

// ---------------------------------------------------------------- MFMA GEMM (f16 in, f32 acc)
// C[M,N] = act(A[M,K] @ W[K,N] + bias[N]); ACT 0=none 1=exact gelu
// Block tile 128x64, BK=32, 4 waves as 2x2 (each wave 64x32 = 4x2 frags of 16x16).
// Fragment k-order note: A and B frags are both loaded as contiguous 8-f16 K-runs
// from row-major [row][K] LDS tiles; any internal k-permutation cancels since both
// operands use the identical mapping. C/D layout: col=lane&15, row=(lane>>4)*4+reg.
template<int ACT>
__global__ __launch_bounds__(256) void mfma_gemm_kernel(
    const float* __restrict__ A, const float* __restrict__ W,
    const float* __restrict__ bias, float* __restrict__ C,
    int M, int N, int K)
{
    __shared__ _Float16 At[128][40];   // pad to 80B stride: 2-way bank alias = free
    __shared__ _Float16 Wt[64][40];    // holds W^T tile: Wt[n][k]
    const int bm = blockIdx.x * 128, bn = blockIdx.y * 64;
    const int t = threadIdx.x;
    const int lane = t & 63;
    const int wave = t >> 6;
    const int m0 = (wave >> 1) * 64;   // wave row offset in block
    const int n0 = (wave & 1) * 32;    // wave col offset in block
    const int lrow = lane & 15, lhi = lane >> 4;
    f32x4 acc[4][2] = {};

    for (int k0 = 0; k0 < K; k0 += 32) {
        __syncthreads();
        // stage A: rows bm..bm+128, k0..k0+32. thread t: row=t>>1, 16 floats.
        {
            int r = t >> 1, sg = (t & 1) * 16;
            int row = bm + r;
            h8 lo = {}, hi = {};
            if (row < M) {
                const float* src = &A[(size_t)row*K + k0 + sg];
                f4 v0 = *(const f4*)&src[0];
                f4 v1 = *(const f4*)&src[4];
                f4 v2 = *(const f4*)&src[8];
                f4 v3 = *(const f4*)&src[12];
                lo = h8{(_Float16)v0[0],(_Float16)v0[1],(_Float16)v0[2],(_Float16)v0[3],
                        (_Float16)v1[0],(_Float16)v1[1],(_Float16)v1[2],(_Float16)v1[3]};
                hi = h8{(_Float16)v2[0],(_Float16)v2[1],(_Float16)v2[2],(_Float16)v2[3],
                        (_Float16)v3[0],(_Float16)v3[1],(_Float16)v3[2],(_Float16)v3[3]};
            }
            *(h8*)&At[r][sg]     = lo;
            *(h8*)&At[r][sg + 8] = hi;
        }
        // stage W transposed: thread t reads 8 floats of row k, writes a Wt column seg.
        {
            int kk = t >> 3, nseg = (t & 7) * 8;
            const float* src = &W[(size_t)(k0 + kk)*N + bn + nseg];
            #pragma unroll
            for (int i = 0; i < 8; i++) Wt[nseg + i][kk] = (_Float16)src[i];
        }
        __syncthreads();
        h8 af[4], bf[2];
        #pragma unroll
        for (int mf = 0; mf < 4; mf++) af[mf] = *(const h8*)&At[m0 + mf*16 + lrow][lhi*8];
        #pragma unroll
        for (int nf = 0; nf < 2; nf++) bf[nf] = *(const h8*)&Wt[n0 + nf*16 + lrow][lhi*8];
        #pragma unroll
        for (int mf = 0; mf < 4; mf++)
            #pragma unroll
            for (int nf = 0; nf < 2; nf++)
                acc[mf][nf] = __builtin_amdgcn_mfma_f32_16x16x32_f16(af[mf], bf[nf], acc[mf][nf], 0, 0, 0);
    }

    #pragma unroll
    for (int nf = 0; nf < 2; nf++) {
        int col = bn + n0 + nf*16 + lrow;
        float bv = bias[col];
        #pragma unroll
        for (int mf = 0; mf < 4; mf++) {
            #pragma unroll
            for (int r = 0; r < 4; r++) {
                int row = bm + m0 + mf*16 + lhi*4 + r;
                if (row < M) {
                    float v = acc[mf][nf][r] + bv;
                    if (ACT == 1) v = 0.5f * v * (1.f + erff(v * 0.70710678118654752f));
                    C[(size_t)row*N + col] = v;
                }
            }
        }
    }
}

// ---------------------------------------------------------------- flash attention (fp32)
__global__ __launch_bounds__(256) void attn_kernel(
    const float* __restrict__ Q, const float* __restrict__ K,
    const float* __restrict__ V, const int* __restrict__ enc,
    float* __restrict__ O)
{
    __shared__ float Qs[32][68];
    __shared__ float Ks[32][68];
    __shared__ float Vs[32][68];
    __shared__ float Ps[32][33];
    const int qt = blockIdx.x, h = blockIdx.y, b = blockIdx.z;
    const int q0 = qt * 32;
    const int t = threadIdx.x;
    const int qr = t >> 3;          // my q row; lanes 8qr..8qr+7 = row group (in-wave)
    const int kg = t & 7;
    const int dbase = kg * 8;

    #pragma unroll
    for (int i = 0; i < 2; i++) {
        int e = t + i*256;
        int r = e >> 4, c4 = (e & 15) * 4;
        int s = q0 + r;
        f4 v = {0.f,0.f,0.f,0.f};
        if (s < NS) v = *(const f4*)&Q[(size_t)(b*NS + s)*512 + h*64 + c4];
        *(f4*)&Qs[r][c4] = v;
    }
    float m = -INFINITY, l = 0.f;
    float o[8] = {};
    for (int kt = 0; kt < 25; kt++) {
        int k0 = kt * 32;
        __syncthreads();
        #pragma unroll
        for (int i = 0; i < 2; i++) {
            int e = t + i*256;
            int r = e >> 4, c4 = (e & 15) * 4;
            int s = k0 + r;
            f4 kv = {0.f,0.f,0.f,0.f}, vv = {0.f,0.f,0.f,0.f};
            if (s < NS) {
                kv = *(const f4*)&K[(size_t)(b*NS + s)*512 + h*64 + c4];
                vv = *(const f4*)&V[(size_t)(b*NS + s)*512 + h*64 + c4];
            }
            *(f4*)&Ks[r][c4] = kv;
            *(f4*)&Vs[r][c4] = vv;
        }
        __syncthreads();
        float sc[4] = {0.f,0.f,0.f,0.f};
        #pragma unroll 4
        for (int dd = 0; dd < 64; dd += 4) {
            f4 qv = *(const f4*)&Qs[qr][dd];
            #pragma unroll
            for (int j = 0; j < 4; j++) {
                f4 kv = *(const f4*)&Ks[kg*4 + j][dd];
                sc[j] += qv[0]*kv[0] + qv[1]*kv[1] + qv[2]*kv[2] + qv[3]*kv[3];
            }
        }
        float mt = -INFINITY;
        #pragma unroll
        for (int j = 0; j < 4; j++) {
            int kk = k0 + kg*4 + j;
            float v_ = sc[j] * 0.125f;
            if (kk >= NS) v_ = -INFINITY;
            else if (enc[b*NS + kk] == 0) v_ = -1e9f;
            sc[j] = v_;
            mt = fmaxf(mt, v_);
        }
        mt = fmaxf(mt, __shfl_xor(mt, 1));
        mt = fmaxf(mt, __shfl_xor(mt, 2));
        mt = fmaxf(mt, __shfl_xor(mt, 4));
        float mnew = fmaxf(m, mt);
        float corr = expf(m - mnew);
        float ps = 0.f;
        #pragma unroll
        for (int j = 0; j < 4; j++) {
            float p = expf(sc[j] - mnew);
            ps += p;
            Ps[qr][kg*4 + j] = p;   // row group is wave-internal: in-order LDS
        }
        ps += __shfl_xor(ps, 1);
        ps += __shfl_xor(ps, 2);
        ps += __shfl_xor(ps, 4);
        l = l * corr + ps;
        m = mnew;
        #pragma unroll
        for (int jj = 0; jj < 8; jj++) o[jj] *= corr;
        #pragma unroll 8
        for (int kk = 0; kk < 32; kk++) {
            float pv = Ps[qr][kk];
            f4 v0 = *(const f4*)&Vs[kk][dbase];
            f4 v1 = *(const f4*)&Vs[kk][dbase+4];
            o[0] += pv*v0[0]; o[1] += pv*v0[1]; o[2] += pv*v0[2]; o[3] += pv*v0[3];
            o[4] += pv*v1[0]; o[5] += pv*v1[1]; o[6] += pv*v1[2]; o[7] += pv*v1[3];
        }
    }
    int s = q0 + qr;
    if (s < NS) {
        float linv = 1.f / l;
        f4 o0 = {o[0]*linv, o[1]*linv, o[2]*linv, o[3]*linv};
        f4 o1 = {o[4]*linv, o[5]*linv, o[6]*linv, o[7]*linv};
        *(f4*)&O[(size_t)(b*NS + s)*512 + h*64 + dbase]     = o0;
        *(f4*)&O[(size_t)(b*NS + s)*512 + h*64 + dbase + 4] = o1;
    }
}

// ---------------------------------------------------------------- residual + LN
__global__ __launch_bounds__(256) void res_ln_kernel(
    const float* X, const float* __restrict__ R,
    const float* __restrict__ g, const float* __restrict__ be, float* out)
{
    int row = blockIdx.x*4 + (threadIdx.x >> 6);
    int lane = threadIdx.x & 63;
    const float* xr = X + (size_t)row*128;
    const float* rr = R + (size_t)row*128;
    float a0 = xr[lane] + rr[lane];
    float a1 = xr[lane+64] + rr[lane+64];
    float s = a0 + a1;
    for (int o = 1; o < 64; o <<= 1) s += __shfl_xor(s, o);
    float mean = s * (1.f/128.f);
    float e0 = a0 - mean, e1 = a1 - mean;
    float vs = e0*e0 + e1*e1;
    for (int o = 1; o < 64; o <<= 1) vs += __shfl_xor(vs, o);
    float rstd = rsqrtf(vs * (1.f/128.f) + 1e-12f);
    out[(size_t)row*128 + lane]      = e0*rstd*g[lane] + be[lane];
    out[(size_t)row*128 + lane + 64] = e1*rstd*g[lane+64] + be[lane+64];
}

// ---------------------------------------------------------------- head
__global__ __launch_bounds__(512) void head_kernel(
    const float* __restrict__ xs, const float* __restrict__ w1,
    const float* __restrict__ w2, float* __restrict__ out)
{
    __shared__ float red[8];
    int b = blockIdx.x, j = threadIdx.x;
    const float* xr = xs + (size_t)(b*NS)*128;
    float acc = 0.f;
    #pragma unroll 8
    for (int c = 0; c < 128; c++) acc += xr[c] * w1[c*512 + j];
    acc = fmaxf(acc, 0.f);
    float sv = acc * w2[j];
    for (int o = 1; o < 64; o <<= 1) sv += __shfl_xor(sv, o);
    if ((j & 63) == 0) red[j >> 6] = sv;
    __syncthreads();
    if (j == 0) {
        float r = 0.f;
        #pragma unroll
        for (int i = 0; i < 8; i++) r += red[i];
        out[b] = r;
    }
}

// ---------------------------------------------------------------- launch
extern "C" void kernel_launch(void* const* d_in, const int* in_sizes, int n_in,
                              void* d_out, int out_size, void* d_ws, size_t ws_size,
                              hipStream_t stream)
{
    const float* conv_w   = (const float*)d_in[0];
    const float* bn_gamma = (const float*)d_in[1];
    const float* bn_beta  = (const float*)d_in[2];
    const float* bn_mean  = (const float*)d_in[3];
    const float* bn_var   = (const float*)d_in[4];
    const float* pos_emb  = (const float*)d_in[5];
    const float* cls_tok  = (const float*)d_in[6];
    const float* Wq = (const float*)d_in[7];  const float* bq = (const float*)d_in[8];
    const float* Wk = (const float*)d_in[9];  const float* bk = (const float*)d_in[10];
    const float* Wv = (const float*)d_in[11]; const float* bv = (const float*)d_in[12];
    const float* Wo = (const float*)d_in[13]; const float* bo = (const float*)d_in[14];
    const float* ln1_g = (const float*)d_in[15]; const float* ln1_b = (const float*)d_in[16];
    const float* fw1 = (const float*)d_in[17]; const float* fb1 = (const float*)d_in[18];
    const float* fw2 = (const float*)d_in[19]; const float* fb2 = (const float*)d_in[20];
    const float* ln2_g = (const float*)d_in[21]; const float* ln2_b = (const float*)d_in[22];
    const float* pw1 = (const float*)d_in[23]; const float* pw2 = (const float*)d_in[24];
    const int*   enc = (const int*)d_in[25];
    const float* x   = (const float*)d_in[26];
    const float* y   = (const float*)d_in[27];
    float* out = (float*)d_out;

    float* ws = (float*)d_ws;
    float* maxv = ws;                       // 64 floats reserved
    float* xs  = ws + 64;                   // [6280][128]
    float* xf  = xs + 803840;               // [6280][128]
    float* qb  = xf + 803840;               // [6280][512]
    float* kb  = qb + 3215360;
    float* vb  = kb + 3215360;
    float* ctx = vb + 3215360;
    float* encx = qb;                       // stem outputs reuse q/k buffers
    float* ency = kb;

    hipMemsetAsync(d_ws, 0, 256, stream);   // zero maxval

    dim3 cgrid(49, NB);
    conv_bn_relu_kernel<<<cgrid, 256, 0, stream>>>(x, conv_w, bn_gamma, bn_beta,
        bn_mean, bn_var, encx, (unsigned int*)maxv);
    conv_bn_relu_kernel<<<cgrid, 256, 0, stream>>>(y, conv_w, bn_gamma, bn_beta,
        bn_mean, bn_var, ency, (unsigned int*)maxv);

    assemble_kernel<<<3140, 256, 0, stream>>>(encx, ency, cls_tok, pos_emb, maxv, xs, xf);

    for (int i = 0; i < NL; i++) {
        const size_t wofs = (size_t)i * 128 * 512;
        mfma_gemm_kernel<0><<<dim3(50,8), 256, 0, stream>>>(xf, Wq + wofs, bq + i*512, qb, NM, 512, 128);
        mfma_gemm_kernel<0><<<dim3(50,8), 256, 0, stream>>>(xs, Wk + wofs, bk + i*512, kb, NM, 512, 128);
        mfma_gemm_kernel<0><<<dim3(50,8), 256, 0, stream>>>(xs, Wv + wofs, bv + i*512, vb, NM, 512, 128);
        attn_kernel<<<dim3(25,8,8), 256, 0, stream>>>(qb, kb, vb, enc, ctx);
        mfma_gemm_kernel<0><<<dim3(50,2), 256, 0, stream>>>(ctx, Wo + wofs, bo + i*128, vb, NM, 128, 512);
        res_ln_kernel<<<1570, 256, 0, stream>>>(xs, vb, ln1_g + i*128, ln1_b + i*128, xs);
        mfma_gemm_kernel<1><<<dim3(50,8), 256, 0, stream>>>(xs, fw1 + wofs, fb1 + i*512, qb, NM, 512, 128);
        mfma_gemm_kernel<0><<<dim3(50,2), 256, 0, stream>>>(qb, fw2 + wofs, fb2 + i*128, kb, NM, 128, 512);
        res_ln_kernel<<<1570, 256, 0, stream>>>(xs, kb, ln2_g + i*128, ln2_b + i*128, xs);
    }

    head_kernel<<<8, 512, 0, stream>>>(xs, pw1, pw2, out);
}

// Round 5
// 1239.980 us; speedup vs baseline: 2.4231x; 2.4231x over previous
//
#include <hip/hip_runtime.h>
#include <hip/hip_bf16.h>
#include <math.h>

typedef float f4 __attribute__((ext_vector_type(4)));
typedef _Float16 h8 __attribute__((ext_vector_type(8)));
typedef float f32x4 __attribute__((ext_vector_type(4)));

#define NB 8
#define NS 785
#define ND 128
#define NH 8
#define NDH 64
#define NDF 512
#define NL 6
#define NP 784
#define NCIN 512
#define NM (NB*NS)   // 6280

// ---------------------------------------------------------------- conv stem
__global__ __launch_bounds__(256) void conv_bn_relu_kernel(
    const float* __restrict__ x, const float* __restrict__ w,
    const float* __restrict__ gamma, const float* __restrict__ beta,
    const float* __restrict__ mean, const float* __restrict__ var,
    float* __restrict__ enc, unsigned int* __restrict__ maxv)
{
    __shared__ float xt[64][17];    // [c][p]
    __shared__ float wt[64][132];   // [c][d]
    __shared__ float red[4];
    const int b  = blockIdx.y;
    const int p0 = blockIdx.x * 16;       // 49*16 = 784 exact
    const int t  = threadIdx.x;
    const int pl = (t & 3) * 4;           // 4 pixels
    const int dl = (t >> 2) * 2;          // 2 channels
    float acc[2][4] = {};
    for (int c0 = 0; c0 < NCIN; c0 += 64) {
        __syncthreads();
        {
            int cc = t >> 2, pp = (t & 3) * 4;
            f4 v = *(const f4*)&x[(size_t)(b*NCIN + c0 + cc)*NP + p0 + pp];
            xt[cc][pp+0] = v[0]; xt[cc][pp+1] = v[1]; xt[cc][pp+2] = v[2]; xt[cc][pp+3] = v[3];
        }
        #pragma unroll
        for (int i = 0; i < 8; i++) {
            int e = t + i*256;
            int d = e >> 4, c4 = (e & 15) * 4;
            f4 v = *(const f4*)&w[(size_t)d*NCIN + c0 + c4];
            wt[c4+0][d] = v[0]; wt[c4+1][d] = v[1]; wt[c4+2][d] = v[2]; wt[c4+3][d] = v[3];
        }
        __syncthreads();
        #pragma unroll 8
        for (int cc = 0; cc < 64; cc++) {
            float w0 = wt[cc][dl], w1 = wt[cc][dl+1];
            float x0 = xt[cc][pl+0], x1 = xt[cc][pl+1], x2 = xt[cc][pl+2], x3 = xt[cc][pl+3];
            acc[0][0] += w0*x0; acc[0][1] += w0*x1; acc[0][2] += w0*x2; acc[0][3] += w0*x3;
            acc[1][0] += w1*x0; acc[1][1] += w1*x1; acc[1][2] += w1*x2; acc[1][3] += w1*x3;
        }
    }
    float lmax = 0.f;
    #pragma unroll
    for (int i = 0; i < 2; i++) {
        int d = dl + i;
        float inv = rsqrtf(var[d] + 1e-5f);
        float sc = gamma[d] * inv;
        float sh = beta[d] - mean[d] * sc;
        #pragma unroll
        for (int j = 0; j < 4; j++) {
            float vo = fmaxf(acc[i][j]*sc + sh, 0.f);
            lmax = fmaxf(lmax, vo);
            enc[(size_t)(b*NP + p0 + pl + j)*ND + d] = vo;
        }
    }
    for (int o = 1; o < 64; o <<= 1) lmax = fmaxf(lmax, __shfl_xor(lmax, o));
    if ((t & 63) == 0) red[t >> 6] = lmax;
    __syncthreads();
    if (t == 0) {
        float m2 = fmaxf(fmaxf(red[0], red[1]), fmaxf(red[2], red[3]));
        atomicMax(maxv, __float_as_uint(m2));
    }
}

// ---------------------------------------------------------------- assemble xs/xf
__global__ void assemble_kernel(
    const float* __restrict__ encx, const float* __restrict__ ency,
    const float* __restrict__ cls, const float* __restrict__ pos,
    const float* __restrict__ maxv, float* __restrict__ xs, float* __restrict__ xf)
{
    int i = blockIdx.x*256 + threadIdx.x;   // < 8*785*128 = 803840 exact
    int d = i & 127;
    int s = (i >> 7) % NS;
    int b = i / (NS*ND);
    float inv = 1.f / maxv[0];
    float pv = pos[s*ND + d];
    float xv, yv;
    if (s == 0) { xv = cls[d]; yv = cls[d]; }
    else {
        int idx = (b*NP + s - 1)*ND + d;
        xv = encx[idx]*inv; yv = ency[idx]*inv;
    }
    xs[i] = xv + pv;
    xf[i] = yv + pv;
}

// ---------------------------------------------------------------- MFMA GEMM (f16 in, f32 acc)
// C[M,N] = act(A[M,K] @ W[K,N] + bias[N]); ACT 0=none 1=exact gelu
// Validated on HW in round 3 (passed). A/B frags: lane holds row=lane&15,
// k-run=(lane>>4)*8 from row-major [row][K] LDS; C/D: col=lane&15,
// row=(lane>>4)*4+reg.
template<int ACT>
__global__ __launch_bounds__(256) void mfma_gemm_kernel(
    const float* __restrict__ A, const float* __restrict__ W,
    const float* __restrict__ bias, float* __restrict__ C,
    int M, int N, int K)
{
    __shared__ _Float16 At[128][40];
    __shared__ _Float16 Wt[64][40];    // W^T tile: Wt[n][k]
    const int bm = blockIdx.x * 128, bn = blockIdx.y * 64;
    const int t = threadIdx.x;
    const int lane = t & 63;
    const int wave = t >> 6;
    const int m0 = (wave >> 1) * 64;
    const int n0 = (wave & 1) * 32;
    const int lrow = lane & 15, lhi = lane >> 4;
    f32x4 acc[4][2] = {};

    for (int k0 = 0; k0 < K; k0 += 32) {
        __syncthreads();
        {
            int r = t >> 1, sg = (t & 1) * 16;
            int row = bm + r;
            h8 lo = {}, hi = {};
            if (row < M) {
                const float* src = &A[(size_t)row*K + k0 + sg];
                f4 v0 = *(const f4*)&src[0];
                f4 v1 = *(const f4*)&src[4];
                f4 v2 = *(const f4*)&src[8];
                f4 v3 = *(const f4*)&src[12];
                lo = h8{(_Float16)v0[0],(_Float16)v0[1],(_Float16)v0[2],(_Float16)v0[3],
                        (_Float16)v1[0],(_Float16)v1[1],(_Float16)v1[2],(_Float16)v1[3]};
                hi = h8{(_Float16)v2[0],(_Float16)v2[1],(_Float16)v2[2],(_Float16)v2[3],
                        (_Float16)v3[0],(_Float16)v3[1],(_Float16)v3[2],(_Float16)v3[3]};
            }
            *(h8*)&At[r][sg]     = lo;
            *(h8*)&At[r][sg + 8] = hi;
        }
        {
            int kk = t >> 3, nseg = (t & 7) * 8;
            const float* src = &W[(size_t)(k0 + kk)*N + bn + nseg];
            #pragma unroll
            for (int i = 0; i < 8; i++) Wt[nseg + i][kk] = (_Float16)src[i];
        }
        __syncthreads();
        h8 af[4], bf[2];
        #pragma unroll
        for (int mf = 0; mf < 4; mf++) af[mf] = *(const h8*)&At[m0 + mf*16 + lrow][lhi*8];
        #pragma unroll
        for (int nf = 0; nf < 2; nf++) bf[nf] = *(const h8*)&Wt[n0 + nf*16 + lrow][lhi*8];
        #pragma unroll
        for (int mf = 0; mf < 4; mf++)
            #pragma unroll
            for (int nf = 0; nf < 2; nf++)
                acc[mf][nf] = __builtin_amdgcn_mfma_f32_16x16x32_f16(af[mf], bf[nf], acc[mf][nf], 0, 0, 0);
    }

    #pragma unroll
    for (int nf = 0; nf < 2; nf++) {
        int col = bn + n0 + nf*16 + lrow;
        float bv = bias[col];
        #pragma unroll
        for (int mf = 0; mf < 4; mf++) {
            #pragma unroll
            for (int r = 0; r < 4; r++) {
                int row = bm + m0 + mf*16 + lhi*4 + r;
                if (row < M) {
                    float v = acc[mf][nf][r] + bv;
                    if (ACT == 1) v = 0.5f * v * (1.f + erff(v * 0.70710678118654752f));
                    C[(size_t)row*N + col] = v;
                }
            }
        }
    }
}

// ---------------------------------------------------------------- MFMA flash attention
// Q,K,V layout [b][s][h*64+d] f32. Block: 64 q-rows, 4 waves x 16 q-rows.
// K/V tiles of 64 staged f16 (V transposed). Same frag conventions as GEMM.
__global__ __launch_bounds__(256) void attn_mfma_kernel(
    const float* __restrict__ Q, const float* __restrict__ K,
    const float* __restrict__ V, const int* __restrict__ enc,
    float* __restrict__ O)
{
    __shared__ _Float16 Ks[64][68];      // [k][d], pad 68 -> conflict-free frag reads
    __shared__ _Float16 Vt[64][68];      // [d][k]
    __shared__ _Float16 Ps[4][16][68];   // per-wave P tile [q][k]
    const int qt = blockIdx.x, h = blockIdx.y, b = blockIdx.z;
    const int q0 = qt * 64;
    const int t = threadIdx.x, lane = t & 63, w = t >> 6;
    const int lrow = lane & 15, lhi = lane >> 4;

    // Q fragments direct to regs (loaded once): q-row = q0+w*16+lrow, d-runs lhi*8(+32)
    h8 qf[2] = {};
    {
        int qrow = q0 + w*16 + lrow;
        if (qrow < NS) {
            const float* src = &Q[(size_t)(b*NS + qrow)*512 + h*64];
            #pragma unroll
            for (int ks = 0; ks < 2; ks++) {
                f4 a = *(const f4*)&src[ks*32 + lhi*8];
                f4 c = *(const f4*)&src[ks*32 + lhi*8 + 4];
                qf[ks] = h8{(_Float16)a[0],(_Float16)a[1],(_Float16)a[2],(_Float16)a[3],
                            (_Float16)c[0],(_Float16)c[1],(_Float16)c[2],(_Float16)c[3]};
            }
        }
    }

    float m[4], l[4];
    f32x4 acc[4] = {};   // [d-frag]; col=lane&15 -> d, row regs -> q (same layout as softmax state)
    #pragma unroll
    for (int r = 0; r < 4; r++) { m[r] = -INFINITY; l[r] = 0.f; }

    for (int kt = 0; kt < 13; kt++) {
        int k0 = kt * 64;
        __syncthreads();
        // stage K tile: thread t -> row r=t>>2, 16 d-cols at (t&3)*16
        {
            int r = t >> 2, c0 = (t & 3) * 16;
            int s = k0 + r;
            h8 lo = {}, hi = {};
            if (s < NS) {
                const float* src = &K[(size_t)(b*NS + s)*512 + h*64 + c0];
                f4 v0 = *(const f4*)&src[0];
                f4 v1 = *(const f4*)&src[4];
                f4 v2 = *(const f4*)&src[8];
                f4 v3 = *(const f4*)&src[12];
                lo = h8{(_Float16)v0[0],(_Float16)v0[1],(_Float16)v0[2],(_Float16)v0[3],
                        (_Float16)v1[0],(_Float16)v1[1],(_Float16)v1[2],(_Float16)v1[3]};
                hi = h8{(_Float16)v2[0],(_Float16)v2[1],(_Float16)v2[2],(_Float16)v2[3],
                        (_Float16)v3[0],(_Float16)v3[1],(_Float16)v3[2],(_Float16)v3[3]};
            }
            *(h8*)&Ks[r][c0]     = lo;
            *(h8*)&Ks[r][c0 + 8] = hi;
        }
        // stage V transposed: Vt[d][k]
        {
            int r = t >> 2, c0 = (t & 3) * 16;
            int s = k0 + r;
            if (s < NS) {
                const float* src = &V[(size_t)(b*NS + s)*512 + h*64 + c0];
                #pragma unroll
                for (int i = 0; i < 16; i++) Vt[c0 + i][r] = (_Float16)src[i];
            } else {
                #pragma unroll
                for (int i = 0; i < 16; i++) Vt[c0 + i][r] = (_Float16)0.f;
            }
        }
        __syncthreads();

        // QK^T: S[q 16][k 64] per wave. sc[nf]: col=lane&15 -> k-col nf*16+lrow, rows=q.
        f32x4 sc[4] = {};
        #pragma unroll
        for (int nf = 0; nf < 4; nf++)
            #pragma unroll
            for (int ks = 0; ks < 2; ks++) {
                h8 bf = *(const h8*)&Ks[nf*16 + lrow][ks*32 + lhi*8];
                sc[nf] = __builtin_amdgcn_mfma_f32_16x16x32_f16(qf[ks], bf, sc[nf], 0, 0, 0);
            }
        // scale + mask (mask depends only on k-col = same for all 4 regs)
        #pragma unroll
        for (int nf = 0; nf < 4; nf++) {
            int kk = k0 + nf*16 + lrow;
            bool oob = (kk >= NS);
            float madd = (!oob && enc[b*NS + kk] == 0) ? -1e9f : 0.f;
            #pragma unroll
            for (int r = 0; r < 4; r++) {
                float v = sc[nf][r] * 0.125f + madd;
                sc[nf][r] = oob ? -INFINITY : v;
            }
        }
        // online softmax per q-row (rows live in regs; k spreads over 16 lanes + 4 frags)
        float corr[4];
        #pragma unroll
        for (int r = 0; r < 4; r++) {
            float mt = fmaxf(fmaxf(sc[0][r], sc[1][r]), fmaxf(sc[2][r], sc[3][r]));
            mt = fmaxf(mt, __shfl_xor(mt, 1));
            mt = fmaxf(mt, __shfl_xor(mt, 2));
            mt = fmaxf(mt, __shfl_xor(mt, 4));
            mt = fmaxf(mt, __shfl_xor(mt, 8));
            float mn = fmaxf(m[r], mt);
            corr[r] = __expf(m[r] - mn);      // tile 0 always yields finite mn
            m[r] = mn;
            float ps = 0.f;
            #pragma unroll
            for (int nf = 0; nf < 4; nf++) {
                float p = __expf(sc[nf][r] - mn);
                sc[nf][r] = p;
                ps += p;
            }
            ps += __shfl_xor(ps, 1);
            ps += __shfl_xor(ps, 2);
            ps += __shfl_xor(ps, 4);
            ps += __shfl_xor(ps, 8);
            l[r] = l[r] * corr[r] + ps;
        }
        // P -> LDS f16 (wave-local buffer): row=q=lhi*4+r, col=k=nf*16+lrow
        #pragma unroll
        for (int nf = 0; nf < 4; nf++)
            #pragma unroll
            for (int r = 0; r < 4; r++)
                Ps[w][lhi*4 + r][nf*16 + lrow] = (_Float16)sc[nf][r];
        // wave-local write->read fence (rule #18: waitcnt + sched_barrier)
        asm volatile("s_waitcnt lgkmcnt(0)" ::: "memory");
        __builtin_amdgcn_sched_barrier(0);
        // rescale O, then PV: O[q][d] += P[q][k] * Vt[d][k]
        #pragma unroll
        for (int nf = 0; nf < 4; nf++)
            #pragma unroll
            for (int r = 0; r < 4; r++) acc[nf][r] *= corr[r];
        #pragma unroll
        for (int nf = 0; nf < 4; nf++)
            #pragma unroll
            for (int ks = 0; ks < 2; ks++) {
                h8 pf = *(const h8*)&Ps[w][lrow][ks*32 + lhi*8];
                h8 vf = *(const h8*)&Vt[nf*16 + lrow][ks*32 + lhi*8];
                acc[nf] = __builtin_amdgcn_mfma_f32_16x16x32_f16(pf, vf, acc[nf], 0, 0, 0);
            }
    }
    // epilogue: row=q0+w*16+lhi*4+r, col=h*64+nf*16+lrow (16 lanes -> 64B coalesced)
    #pragma unroll
    for (int nf = 0; nf < 4; nf++)
        #pragma unroll
        for (int r = 0; r < 4; r++) {
            int row = q0 + w*16 + lhi*4 + r;
            if (row < NS)
                O[(size_t)(b*NS + row)*512 + h*64 + nf*16 + lrow] = acc[nf][r] / l[r];
        }
}

// ---------------------------------------------------------------- residual + LN
__global__ __launch_bounds__(256) void res_ln_kernel(
    const float* X, const float* __restrict__ R,
    const float* __restrict__ g, const float* __restrict__ be, float* out)
{
    int row = blockIdx.x*4 + (threadIdx.x >> 6);
    int lane = threadIdx.x & 63;
    const float* xr = X + (size_t)row*128;
    const float* rr = R + (size_t)row*128;
    float a0 = xr[lane] + rr[lane];
    float a1 = xr[lane+64] + rr[lane+64];
    float s = a0 + a1;
    for (int o = 1; o < 64; o <<= 1) s += __shfl_xor(s, o);
    float mean = s * (1.f/128.f);
    float e0 = a0 - mean, e1 = a1 - mean;
    float vs = e0*e0 + e1*e1;
    for (int o = 1; o < 64; o <<= 1) vs += __shfl_xor(vs, o);
    float rstd = rsqrtf(vs * (1.f/128.f) + 1e-12f);
    out[(size_t)row*128 + lane]      = e0*rstd*g[lane] + be[lane];
    out[(size_t)row*128 + lane + 64] = e1*rstd*g[lane+64] + be[lane+64];
}

// ---------------------------------------------------------------- head
__global__ __launch_bounds__(512) void head_kernel(
    const float* __restrict__ xs, const float* __restrict__ w1,
    const float* __restrict__ w2, float* __restrict__ out)
{
    __shared__ float red[8];
    int b = blockIdx.x, j = threadIdx.x;
    const float* xr = xs + (size_t)(b*NS)*128;
    float acc = 0.f;
    #pragma unroll 8
    for (int c = 0; c < 128; c++) acc += xr[c] * w1[c*512 + j];
    acc = fmaxf(acc, 0.f);
    float sv = acc * w2[j];
    for (int o = 1; o < 64; o <<= 1) sv += __shfl_xor(sv, o);
    if ((j & 63) == 0) red[j >> 6] = sv;
    __syncthreads();
    if (j == 0) {
        float r = 0.f;
        #pragma unroll
        for (int i = 0; i < 8; i++) r += red[i];
        out[b] = r;
    }
}

// ---------------------------------------------------------------- launch
extern "C" void kernel_launch(void* const* d_in, const int* in_sizes, int n_in,
                              void* d_out, int out_size, void* d_ws, size_t ws_size,
                              hipStream_t stream)
{
    const float* conv_w   = (const float*)d_in[0];
    const float* bn_gamma = (const float*)d_in[1];
    const float* bn_beta  = (const float*)d_in[2];
    const float* bn_mean  = (const float*)d_in[3];
    const float* bn_var   = (const float*)d_in[4];
    const float* pos_emb  = (const float*)d_in[5];
    const float* cls_tok  = (const float*)d_in[6];
    const float* Wq = (const float*)d_in[7];  const float* bq = (const float*)d_in[8];
    const float* Wk = (const float*)d_in[9];  const float* bk = (const float*)d_in[10];
    const float* Wv = (const float*)d_in[11]; const float* bv = (const float*)d_in[12];
    const float* Wo = (const float*)d_in[13]; const float* bo = (const float*)d_in[14];
    const float* ln1_g = (const float*)d_in[15]; const float* ln1_b = (const float*)d_in[16];
    const float* fw1 = (const float*)d_in[17]; const float* fb1 = (const float*)d_in[18];
    const float* fw2 = (const float*)d_in[19]; const float* fb2 = (const float*)d_in[20];
    const float* ln2_g = (const float*)d_in[21]; const float* ln2_b = (const float*)d_in[22];
    const float* pw1 = (const float*)d_in[23]; const float* pw2 = (const float*)d_in[24];
    const int*   enc = (const int*)d_in[25];
    const float* x   = (const float*)d_in[26];
    const float* y   = (const float*)d_in[27];
    float* out = (float*)d_out;

    float* ws = (float*)d_ws;
    float* maxv = ws;                       // 64 floats reserved
    float* xs  = ws + 64;                   // [6280][128]
    float* xf  = xs + 803840;               // [6280][128]
    float* qb  = xf + 803840;               // [6280][512]
    float* kb  = qb + 3215360;
    float* vb  = kb + 3215360;
    float* ctx = vb + 3215360;
    float* encx = qb;                       // stem outputs reuse q/k buffers
    float* ency = kb;

    hipMemsetAsync(d_ws, 0, 256, stream);   // zero maxval

    dim3 cgrid(49, NB);
    conv_bn_relu_kernel<<<cgrid, 256, 0, stream>>>(x, conv_w, bn_gamma, bn_beta,
        bn_mean, bn_var, encx, (unsigned int*)maxv);
    conv_bn_relu_kernel<<<cgrid, 256, 0, stream>>>(y, conv_w, bn_gamma, bn_beta,
        bn_mean, bn_var, ency, (unsigned int*)maxv);

    assemble_kernel<<<3140, 256, 0, stream>>>(encx, ency, cls_tok, pos_emb, maxv, xs, xf);

    for (int i = 0; i < NL; i++) {
        const size_t wofs = (size_t)i * 128 * 512;
        mfma_gemm_kernel<0><<<dim3(50,8), 256, 0, stream>>>(xf, Wq + wofs, bq + i*512, qb, NM, 512, 128);
        mfma_gemm_kernel<0><<<dim3(50,8), 256, 0, stream>>>(xs, Wk + wofs, bk + i*512, kb, NM, 512, 128);
        mfma_gemm_kernel<0><<<dim3(50,8), 256, 0, stream>>>(xs, Wv + wofs, bv + i*512, vb, NM, 512, 128);
        attn_mfma_kernel<<<dim3(13,8,8), 256, 0, stream>>>(qb, kb, vb, enc, ctx);
        mfma_gemm_kernel<0><<<dim3(50,2), 256, 0, stream>>>(ctx, Wo + wofs, bo + i*128, vb, NM, 128, 512);
        res_ln_kernel<<<1570, 256, 0, stream>>>(xs, vb, ln1_g + i*128, ln1_b + i*128, xs);
        mfma_gemm_kernel<1><<<dim3(50,8), 256, 0, stream>>>(xs, fw1 + wofs, fb1 + i*512, qb, NM, 512, 128);
        mfma_gemm_kernel<0><<<dim3(50,2), 256, 0, stream>>>(qb, fw2 + wofs, fb2 + i*128, kb, NM, 128, 512);
        res_ln_kernel<<<1570, 256, 0, stream>>>(xs, kb, ln2_g + i*128, ln2_b + i*128, xs);
    }

    head_kernel<<<8, 512, 0, stream>>>(xs, pw1, pw2, out);
}

// Round 10
// 1212.714 us; speedup vs baseline: 2.4776x; 1.0225x over previous
//
#include <hip/hip_runtime.h>
#include <hip/hip_bf16.h>
#include <math.h>

typedef float f4 __attribute__((ext_vector_type(4)));
typedef _Float16 h8 __attribute__((ext_vector_type(8)));
typedef float f32x4 __attribute__((ext_vector_type(4)));

#define NB 8
#define NS 785
#define ND 128
#define NH 8
#define NDH 64
#define NDF 512
#define NL 6
#define NP 784
#define NCIN 512
#define NM (NB*NS)   // 6280

// ---------------------------------------------------------------- conv stem
__global__ __launch_bounds__(256) void conv_bn_relu_kernel(
    const float* __restrict__ x, const float* __restrict__ w,
    const float* __restrict__ gamma, const float* __restrict__ beta,
    const float* __restrict__ mean, const float* __restrict__ var,
    float* __restrict__ enc, unsigned int* __restrict__ maxv)
{
    __shared__ float xt[64][17];    // [c][p]
    __shared__ float wt[64][132];   // [c][d]
    __shared__ float red[4];
    const int b  = blockIdx.y;
    const int p0 = blockIdx.x * 16;       // 49*16 = 784 exact
    const int t  = threadIdx.x;
    const int pl = (t & 3) * 4;           // 4 pixels
    const int dl = (t >> 2) * 2;          // 2 channels
    float acc[2][4] = {};
    for (int c0 = 0; c0 < NCIN; c0 += 64) {
        __syncthreads();
        {
            int cc = t >> 2, pp = (t & 3) * 4;
            f4 v = *(const f4*)&x[(size_t)(b*NCIN + c0 + cc)*NP + p0 + pp];
            xt[cc][pp+0] = v[0]; xt[cc][pp+1] = v[1]; xt[cc][pp+2] = v[2]; xt[cc][pp+3] = v[3];
        }
        #pragma unroll
        for (int i = 0; i < 8; i++) {
            int e = t + i*256;
            int d = e >> 4, c4 = (e & 15) * 4;
            f4 v = *(const f4*)&w[(size_t)d*NCIN + c0 + c4];
            wt[c4+0][d] = v[0]; wt[c4+1][d] = v[1]; wt[c4+2][d] = v[2]; wt[c4+3][d] = v[3];
        }
        __syncthreads();
        #pragma unroll 8
        for (int cc = 0; cc < 64; cc++) {
            float w0 = wt[cc][dl], w1 = wt[cc][dl+1];
            float x0 = xt[cc][pl+0], x1 = xt[cc][pl+1], x2 = xt[cc][pl+2], x3 = xt[cc][pl+3];
            acc[0][0] += w0*x0; acc[0][1] += w0*x1; acc[0][2] += w0*x2; acc[0][3] += w0*x3;
            acc[1][0] += w1*x0; acc[1][1] += w1*x1; acc[1][2] += w1*x2; acc[1][3] += w1*x3;
        }
    }
    float lmax = 0.f;
    #pragma unroll
    for (int i = 0; i < 2; i++) {
        int d = dl + i;
        float inv = rsqrtf(var[d] + 1e-5f);
        float sc = gamma[d] * inv;
        float sh = beta[d] - mean[d] * sc;
        #pragma unroll
        for (int j = 0; j < 4; j++) {
            float vo = fmaxf(acc[i][j]*sc + sh, 0.f);
            lmax = fmaxf(lmax, vo);
            enc[(size_t)(b*NP + p0 + pl + j)*ND + d] = vo;
        }
    }
    for (int o = 1; o < 64; o <<= 1) lmax = fmaxf(lmax, __shfl_xor(lmax, o));
    if ((t & 63) == 0) red[t >> 6] = lmax;
    __syncthreads();
    if (t == 0) {
        float m2 = fmaxf(fmaxf(red[0], red[1]), fmaxf(red[2], red[3]));
        atomicMax(maxv, __float_as_uint(m2));
    }
}

// ---------------------------------------------------------------- assemble xs/xf
__global__ void assemble_kernel(
    const float* __restrict__ encx, const float* __restrict__ ency,
    const float* __restrict__ cls, const float* __restrict__ pos,
    const float* __restrict__ maxv, float* __restrict__ xs, float* __restrict__ xf)
{
    int i = blockIdx.x*256 + threadIdx.x;   // < 8*785*128 = 803840 exact
    int d = i & 127;
    int s = (i >> 7) % NS;
    int b = i / (NS*ND);
    float inv = 1.f / maxv[0];
    float pv = pos[s*ND + d];
    float xv, yv;
    if (s == 0) { xv = cls[d]; yv = cls[d]; }
    else {
        int idx = (b*NP + s - 1)*ND + d;
        xv = encx[idx]*inv; yv = ency[idx]*inv;
    }
    xs[i] = xv + pv;
    xf[i] = yv + pv;
}

// ---------------------------------------------------------------- MFMA GEMM (f16 in, f32 acc)
// C[M,N] = act(A[M,K] @ W[K,N] + bias[N]); ACT 0=none 1=exact gelu.
// OUTH: 0 -> C float*, 1 -> C _Float16* (halves write traffic; attn consumes f16).
// HW-validated frag conventions (r3/r5): A/B lane row=lane&15, k-run=(lane>>4)*8
// from row-major [row][K] LDS; C/D col=lane&15, row=(lane>>4)*4+reg.
template<int ACT, int OUTH>
__global__ __launch_bounds__(256) void mfma_gemm_kernel(
    const float* __restrict__ A, const float* __restrict__ W,
    const float* __restrict__ bias, void* __restrict__ Cv,
    int M, int N, int K)
{
    __shared__ _Float16 At[128][40];
    __shared__ _Float16 Wt[64][40];    // W^T tile: Wt[n][k]
    const int bm = blockIdx.x * 128, bn = blockIdx.y * 64;
    const int t = threadIdx.x;
    const int lane = t & 63;
    const int wave = t >> 6;
    const int m0 = (wave >> 1) * 64;
    const int n0 = (wave & 1) * 32;
    const int lrow = lane & 15, lhi = lane >> 4;
    f32x4 acc[4][2] = {};

    for (int k0 = 0; k0 < K; k0 += 32) {
        __syncthreads();
        {
            int r = t >> 1, sg = (t & 1) * 16;
            int row = bm + r;
            h8 lo = {}, hi = {};
            if (row < M) {
                const float* src = &A[(size_t)row*K + k0 + sg];
                f4 v0 = *(const f4*)&src[0];
                f4 v1 = *(const f4*)&src[4];
                f4 v2 = *(const f4*)&src[8];
                f4 v3 = *(const f4*)&src[12];
                lo = h8{(_Float16)v0[0],(_Float16)v0[1],(_Float16)v0[2],(_Float16)v0[3],
                        (_Float16)v1[0],(_Float16)v1[1],(_Float16)v1[2],(_Float16)v1[3]};
                hi = h8{(_Float16)v2[0],(_Float16)v2[1],(_Float16)v2[2],(_Float16)v2[3],
                        (_Float16)v3[0],(_Float16)v3[1],(_Float16)v3[2],(_Float16)v3[3]};
            }
            *(h8*)&At[r][sg]     = lo;
            *(h8*)&At[r][sg + 8] = hi;
        }
        {
            int kk = t >> 3, nseg = (t & 7) * 8;
            const float* src = &W[(size_t)(k0 + kk)*N + bn + nseg];
            #pragma unroll
            for (int i = 0; i < 8; i++) Wt[nseg + i][kk] = (_Float16)src[i];
        }
        __syncthreads();
        h8 af[4], bf[2];
        #pragma unroll
        for (int mf = 0; mf < 4; mf++) af[mf] = *(const h8*)&At[m0 + mf*16 + lrow][lhi*8];
        #pragma unroll
        for (int nf = 0; nf < 2; nf++) bf[nf] = *(const h8*)&Wt[n0 + nf*16 + lrow][lhi*8];
        #pragma unroll
        for (int mf = 0; mf < 4; mf++)
            #pragma unroll
            for (int nf = 0; nf < 2; nf++)
                acc[mf][nf] = __builtin_amdgcn_mfma_f32_16x16x32_f16(af[mf], bf[nf], acc[mf][nf], 0, 0, 0);
    }

    #pragma unroll
    for (int nf = 0; nf < 2; nf++) {
        int col = bn + n0 + nf*16 + lrow;
        float bv = bias[col];
        #pragma unroll
        for (int mf = 0; mf < 4; mf++) {
            #pragma unroll
            for (int r = 0; r < 4; r++) {
                int row = bm + m0 + mf*16 + lhi*4 + r;
                if (row < M) {
                    float v = acc[mf][nf][r] + bv;
                    if (ACT == 1) v = 0.5f * v * (1.f + erff(v * 0.70710678118654752f));
                    if (OUTH) ((_Float16*)Cv)[(size_t)row*N + col] = (_Float16)v;
                    else      ((float*)Cv)[(size_t)row*N + col] = v;
                }
            }
        }
    }
}

// ---------------------------------------------------------------- MFMA flash attention
// Q,K,V layout [b][s][h*64+d] f16. Block: 64 q-rows, 4 waves x 16 q-rows.
// Grid (b, h, qt): blocks sharing (b,h) are 64 apart in linear id -> same XCD
// (64 % 8 == 0) -> K/V tile re-reads hit that XCD's L2 instead of HBM.
__global__ __launch_bounds__(256) void attn_mfma_kernel(
    const _Float16* __restrict__ Q, const _Float16* __restrict__ K,
    const _Float16* __restrict__ V, const int* __restrict__ enc,
    float* __restrict__ O)
{
    __shared__ _Float16 Ks[64][68];      // [k][d], pad 68 -> conflict-free frag reads
    __shared__ _Float16 Vt[64][68];      // [d][k]
    __shared__ _Float16 Ps[4][16][68];   // per-wave P tile [q][k]
    const int b = blockIdx.x, h = blockIdx.y, qt = blockIdx.z;
    const int q0 = qt * 64;
    const int t = threadIdx.x, lane = t & 63, w = t >> 6;
    const int lrow = lane & 15, lhi = lane >> 4;

    // Q fragments direct to regs (loaded once): q-row = q0+w*16+lrow, d-runs lhi*8(+32)
    h8 qf[2] = {};
    {
        int qrow = q0 + w*16 + lrow;
        if (qrow < NS) {
            const _Float16* src = &Q[(size_t)(b*NS + qrow)*512 + h*64];
            #pragma unroll
            for (int ks = 0; ks < 2; ks++)
                qf[ks] = *(const h8*)&src[ks*32 + lhi*8];
        }
    }

    float m[4], l[4];
    f32x4 acc[4] = {};   // [d-frag]; col=lane&15 -> d, row regs -> q
    #pragma unroll
    for (int r = 0; r < 4; r++) { m[r] = -INFINITY; l[r] = 0.f; }

    for (int kt = 0; kt < 13; kt++) {
        int k0 = kt * 64;
        __syncthreads();
        // stage K tile: thread t -> row r=t>>2, 16 d-cols at (t&3)*16
        {
            int r = t >> 2, c0 = (t & 3) * 16;
            int s = k0 + r;
            h8 lo = {}, hi = {};
            if (s < NS) {
                const _Float16* src = &K[(size_t)(b*NS + s)*512 + h*64 + c0];
                lo = *(const h8*)&src[0];
                hi = *(const h8*)&src[8];
            }
            *(h8*)&Ks[r][c0]     = lo;
            *(h8*)&Ks[r][c0 + 8] = hi;
        }
        // stage V transposed: Vt[d][k]
        {
            int r = t >> 2, c0 = (t & 3) * 16;
            int s = k0 + r;
            h8 a = {}, c = {};
            if (s < NS) {
                const _Float16* src = &V[(size_t)(b*NS + s)*512 + h*64 + c0];
                a = *(const h8*)&src[0];
                c = *(const h8*)&src[8];
            }
            #pragma unroll
            for (int i = 0; i < 8; i++) Vt[c0 + i][r] = a[i];
            #pragma unroll
            for (int i = 0; i < 8; i++) Vt[c0 + 8 + i][r] = c[i];
        }
        __syncthreads();

        // QK^T: S[q 16][k 64] per wave. sc[nf]: col=lane&15 -> k-col nf*16+lrow, rows=q.
        f32x4 sc[4] = {};
        #pragma unroll
        for (int nf = 0; nf < 4; nf++)
            #pragma unroll
            for (int ks = 0; ks < 2; ks++) {
                h8 bf = *(const h8*)&Ks[nf*16 + lrow][ks*32 + lhi*8];
                sc[nf] = __builtin_amdgcn_mfma_f32_16x16x32_f16(qf[ks], bf, sc[nf], 0, 0, 0);
            }
        // scale + mask (mask depends only on k-col = same for all 4 regs)
        #pragma unroll
        for (int nf = 0; nf < 4; nf++) {
            int kk = k0 + nf*16 + lrow;
            bool oob = (kk >= NS);
            float madd = (!oob && enc[b*NS + kk] == 0) ? -1e9f : 0.f;
            #pragma unroll
            for (int r = 0; r < 4; r++) {
                float v = sc[nf][r] * 0.125f + madd;
                sc[nf][r] = oob ? -INFINITY : v;
            }
        }
        // online softmax per q-row (rows live in regs; k spreads over 16 lanes + 4 frags)
        float corr[4];
        #pragma unroll
        for (int r = 0; r < 4; r++) {
            float mt = fmaxf(fmaxf(sc[0][r], sc[1][r]), fmaxf(sc[2][r], sc[3][r]));
            mt = fmaxf(mt, __shfl_xor(mt, 1));
            mt = fmaxf(mt, __shfl_xor(mt, 2));
            mt = fmaxf(mt, __shfl_xor(mt, 4));
            mt = fmaxf(mt, __shfl_xor(mt, 8));
            float mn = fmaxf(m[r], mt);
            corr[r] = __expf(m[r] - mn);      // tile 0 always yields finite mn
            m[r] = mn;
            float ps = 0.f;
            #pragma unroll
            for (int nf = 0; nf < 4; nf++) {
                float p = __expf(sc[nf][r] - mn);
                sc[nf][r] = p;
                ps += p;
            }
            ps += __shfl_xor(ps, 1);
            ps += __shfl_xor(ps, 2);
            ps += __shfl_xor(ps, 4);
            ps += __shfl_xor(ps, 8);
            l[r] = l[r] * corr[r] + ps;
        }
        // P -> LDS f16 (wave-local buffer): row=q=lhi*4+r, col=k=nf*16+lrow
        #pragma unroll
        for (int nf = 0; nf < 4; nf++)
            #pragma unroll
            for (int r = 0; r < 4; r++)
                Ps[w][lhi*4 + r][nf*16 + lrow] = (_Float16)sc[nf][r];
        // wave-local write->read fence (rule #18: waitcnt + sched_barrier)
        asm volatile("s_waitcnt lgkmcnt(0)" ::: "memory");
        __builtin_amdgcn_sched_barrier(0);
        // rescale O, then PV: O[q][d] += P[q][k] * Vt[d][k]
        #pragma unroll
        for (int nf = 0; nf < 4; nf++)
            #pragma unroll
            for (int r = 0; r < 4; r++) acc[nf][r] *= corr[r];
        #pragma unroll
        for (int nf = 0; nf < 4; nf++)
            #pragma unroll
            for (int ks = 0; ks < 2; ks++) {
                h8 pf = *(const h8*)&Ps[w][lrow][ks*32 + lhi*8];
                h8 vf = *(const h8*)&Vt[nf*16 + lrow][ks*32 + lhi*8];
                acc[nf] = __builtin_amdgcn_mfma_f32_16x16x32_f16(pf, vf, acc[nf], 0, 0, 0);
            }
    }
    // epilogue: row=q0+w*16+lhi*4+r, col=h*64+nf*16+lrow
    #pragma unroll
    for (int nf = 0; nf < 4; nf++)
        #pragma unroll
        for (int r = 0; r < 4; r++) {
            int row = q0 + w*16 + lhi*4 + r;
            if (row < NS)
                O[(size_t)(b*NS + row)*512 + h*64 + nf*16 + lrow] = acc[nf][r] / l[r];
        }
}

// ---------------------------------------------------------------- residual + LN
__global__ __launch_bounds__(256) void res_ln_kernel(
    const float* X, const float* __restrict__ R,
    const float* __restrict__ g, const float* __restrict__ be, float* out)
{
    int row = blockIdx.x*4 + (threadIdx.x >> 6);
    int lane = threadIdx.x & 63;
    const float* xr = X + (size_t)row*128;
    const float* rr = R + (size_t)row*128;
    float a0 = xr[lane] + rr[lane];
    float a1 = xr[lane+64] + rr[lane+64];
    float s = a0 + a1;
    for (int o = 1; o < 64; o <<= 1) s += __shfl_xor(s, o);
    float mean = s * (1.f/128.f);
    float e0 = a0 - mean, e1 = a1 - mean;
    float vs = e0*e0 + e1*e1;
    for (int o = 1; o < 64; o <<= 1) vs += __shfl_xor(vs, o);
    float rstd = rsqrtf(vs * (1.f/128.f) + 1e-12f);
    out[(size_t)row*128 + lane]      = e0*rstd*g[lane] + be[lane];
    out[(size_t)row*128 + lane + 64] = e1*rstd*g[lane+64] + be[lane+64];
}

// ---------------------------------------------------------------- head
__global__ __launch_bounds__(512) void head_kernel(
    const float* __restrict__ xs, const float* __restrict__ w1,
    const float* __restrict__ w2, float* __restrict__ out)
{
    __shared__ float red[8];
    int b = blockIdx.x, j = threadIdx.x;
    const float* xr = xs + (size_t)(b*NS)*128;
    float acc = 0.f;
    #pragma unroll 8
    for (int c = 0; c < 128; c++) acc += xr[c] * w1[c*512 + j];
    acc = fmaxf(acc, 0.f);
    float sv = acc * w2[j];
    for (int o = 1; o < 64; o <<= 1) sv += __shfl_xor(sv, o);
    if ((j & 63) == 0) red[j >> 6] = sv;
    __syncthreads();
    if (j == 0) {
        float r = 0.f;
        #pragma unroll
        for (int i = 0; i < 8; i++) r += red[i];
        out[b] = r;
    }
}

// ---------------------------------------------------------------- launch
extern "C" void kernel_launch(void* const* d_in, const int* in_sizes, int n_in,
                              void* d_out, int out_size, void* d_ws, size_t ws_size,
                              hipStream_t stream)
{
    const float* conv_w   = (const float*)d_in[0];
    const float* bn_gamma = (const float*)d_in[1];
    const float* bn_beta  = (const float*)d_in[2];
    const float* bn_mean  = (const float*)d_in[3];
    const float* bn_var   = (const float*)d_in[4];
    const float* pos_emb  = (const float*)d_in[5];
    const float* cls_tok  = (const float*)d_in[6];
    const float* Wq = (const float*)d_in[7];  const float* bq = (const float*)d_in[8];
    const float* Wk = (const float*)d_in[9];  const float* bk = (const float*)d_in[10];
    const float* Wv = (const float*)d_in[11]; const float* bv = (const float*)d_in[12];
    const float* Wo = (const float*)d_in[13]; const float* bo = (const float*)d_in[14];
    const float* ln1_g = (const float*)d_in[15]; const float* ln1_b = (const float*)d_in[16];
    const float* fw1 = (const float*)d_in[17]; const float* fb1 = (const float*)d_in[18];
    const float* fw2 = (const float*)d_in[19]; const float* fb2 = (const float*)d_in[20];
    const float* ln2_g = (const float*)d_in[21]; const float* ln2_b = (const float*)d_in[22];
    const float* pw1 = (const float*)d_in[23]; const float* pw2 = (const float*)d_in[24];
    const int*   enc = (const int*)d_in[25];
    const float* x   = (const float*)d_in[26];
    const float* y   = (const float*)d_in[27];
    float* out = (float*)d_out;

    // workspace layout (floats unless noted):
    float* ws   = (float*)d_ws;
    float* maxv = ws;                         // 64
    float* xs   = ws + 64;                    // [6280][128]
    float* xf   = xs + 803840;                // [6280][128]
    float* ctx  = xf + 803840;                // [6280][512] attn out (f32)
    float* fmid = ctx + 3215360;              // [6280][512] ffn1 out
    float* fout = fmid + 3215360;             // [6280][128] Wo out / ffn2 out
    float* encx = fout + 803840;              // [8*784][128] stem
    float* ency = encx + 802816;
    _Float16* qh = (_Float16*)(ency + 802816);    // [6280][512] f16
    _Float16* kh = qh + 3215360;
    _Float16* vh = kh + 3215360;
    // total ~61 MB

    hipMemsetAsync(d_ws, 0, 256, stream);   // zero maxval

    dim3 cgrid(49, NB);
    conv_bn_relu_kernel<<<cgrid, 256, 0, stream>>>(x, conv_w, bn_gamma, bn_beta,
        bn_mean, bn_var, encx, (unsigned int*)maxv);
    conv_bn_relu_kernel<<<cgrid, 256, 0, stream>>>(y, conv_w, bn_gamma, bn_beta,
        bn_mean, bn_var, ency, (unsigned int*)maxv);

    assemble_kernel<<<3140, 256, 0, stream>>>(encx, ency, cls_tok, pos_emb, maxv, xs, xf);

    for (int i = 0; i < NL; i++) {
        const size_t wofs = (size_t)i * 128 * 512;
        mfma_gemm_kernel<0,1><<<dim3(50,8), 256, 0, stream>>>(xf, Wq + wofs, bq + i*512, qh, NM, 512, 128);
        mfma_gemm_kernel<0,1><<<dim3(50,8), 256, 0, stream>>>(xs, Wk + wofs, bk + i*512, kh, NM, 512, 128);
        mfma_gemm_kernel<0,1><<<dim3(50,8), 256, 0, stream>>>(xs, Wv + wofs, bv + i*512, vh, NM, 512, 128);
        attn_mfma_kernel<<<dim3(8,8,13), 256, 0, stream>>>(qh, kh, vh, enc, ctx);
        mfma_gemm_kernel<0,0><<<dim3(50,2), 256, 0, stream>>>(ctx, Wo + wofs, bo + i*128, fout, NM, 128, 512);
        res_ln_kernel<<<1570, 256, 0, stream>>>(xs, fout, ln1_g + i*128, ln1_b + i*128, xs);
        mfma_gemm_kernel<1,0><<<dim3(50,8), 256, 0, stream>>>(xs, fw1 + wofs, fb1 + i*512, fmid, NM, 512, 128);
        mfma_gemm_kernel<0,0><<<dim3(50,2), 256, 0, stream>>>(fmid, fw2 + wofs, fb2 + i*128, fout, NM, 128, 512);
        res_ln_kernel<<<1570, 256, 0, stream>>>(xs, fout, ln2_g + i*128, ln2_b + i*128, xs);
    }

    head_kernel<<<8, 512, 0, stream>>>(xs, pw1, pw2, out);
}

// Round 11
// 1130.165 us; speedup vs baseline: 2.6586x; 1.0730x over previous
//
#include <hip/hip_runtime.h>
#include <hip/hip_bf16.h>
#include <math.h>

typedef float f4 __attribute__((ext_vector_type(4)));
typedef _Float16 h8 __attribute__((ext_vector_type(8)));
typedef float f32x4 __attribute__((ext_vector_type(4)));

#define NB 8
#define NS 785
#define ND 128
#define NH 8
#define NDH 64
#define NDF 512
#define NL 6
#define NP 784
#define NCIN 512
#define NM (NB*NS)   // 6280

// ---------------------------------------------------------------- conv stem
__global__ __launch_bounds__(256) void conv_bn_relu_kernel(
    const float* __restrict__ x, const float* __restrict__ w,
    const float* __restrict__ gamma, const float* __restrict__ beta,
    const float* __restrict__ mean, const float* __restrict__ var,
    float* __restrict__ enc, unsigned int* __restrict__ maxv)
{
    __shared__ float xt[64][17];    // [c][p]
    __shared__ float wt[64][132];   // [c][d]
    __shared__ float red[4];
    const int b  = blockIdx.y;
    const int p0 = blockIdx.x * 16;       // 49*16 = 784 exact
    const int t  = threadIdx.x;
    const int pl = (t & 3) * 4;           // 4 pixels
    const int dl = (t >> 2) * 2;          // 2 channels
    float acc[2][4] = {};
    for (int c0 = 0; c0 < NCIN; c0 += 64) {
        __syncthreads();
        {
            int cc = t >> 2, pp = (t & 3) * 4;
            f4 v = *(const f4*)&x[(size_t)(b*NCIN + c0 + cc)*NP + p0 + pp];
            xt[cc][pp+0] = v[0]; xt[cc][pp+1] = v[1]; xt[cc][pp+2] = v[2]; xt[cc][pp+3] = v[3];
        }
        #pragma unroll
        for (int i = 0; i < 8; i++) {
            int e = t + i*256;
            int d = e >> 4, c4 = (e & 15) * 4;
            f4 v = *(const f4*)&w[(size_t)d*NCIN + c0 + c4];
            wt[c4+0][d] = v[0]; wt[c4+1][d] = v[1]; wt[c4+2][d] = v[2]; wt[c4+3][d] = v[3];
        }
        __syncthreads();
        #pragma unroll 8
        for (int cc = 0; cc < 64; cc++) {
            float w0 = wt[cc][dl], w1 = wt[cc][dl+1];
            float x0 = xt[cc][pl+0], x1 = xt[cc][pl+1], x2 = xt[cc][pl+2], x3 = xt[cc][pl+3];
            acc[0][0] += w0*x0; acc[0][1] += w0*x1; acc[0][2] += w0*x2; acc[0][3] += w0*x3;
            acc[1][0] += w1*x0; acc[1][1] += w1*x1; acc[1][2] += w1*x2; acc[1][3] += w1*x3;
        }
    }
    float lmax = 0.f;
    #pragma unroll
    for (int i = 0; i < 2; i++) {
        int d = dl + i;
        float inv = rsqrtf(var[d] + 1e-5f);
        float sc = gamma[d] * inv;
        float sh = beta[d] - mean[d] * sc;
        #pragma unroll
        for (int j = 0; j < 4; j++) {
            float vo = fmaxf(acc[i][j]*sc + sh, 0.f);
            lmax = fmaxf(lmax, vo);
            enc[(size_t)(b*NP + p0 + pl + j)*ND + d] = vo;
        }
    }
    for (int o = 1; o < 64; o <<= 1) lmax = fmaxf(lmax, __shfl_xor(lmax, o));
    if ((t & 63) == 0) red[t >> 6] = lmax;
    __syncthreads();
    if (t == 0) {
        float m2 = fmaxf(fmaxf(red[0], red[1]), fmaxf(red[2], red[3]));
        atomicMax(maxv, __float_as_uint(m2));
    }
}

// ---------------------------------------------------------------- weight f32->f16 convert
// 6 matrices of 6*65536 f32 each = 2359296 elements; 393216/256=1536 blocks/type
// -> block-uniform switch, fully coalesced both sides.
__global__ __launch_bounds__(256) void wconv_kernel(
    const float* __restrict__ w0, const float* __restrict__ w1,
    const float* __restrict__ w2, const float* __restrict__ w3,
    const float* __restrict__ w4, const float* __restrict__ w5,
    _Float16* o0, _Float16* o1, _Float16* o2,
    _Float16* o3, _Float16* o4, _Float16* o5)
{
    int t = blockIdx.x*256 + threadIdx.x;     // < 2359296 exact
    int type = t / 393216, off = t % 393216;
    const float* in; _Float16* outp;
    switch (type) {
        case 0: in = w0; outp = o0; break;
        case 1: in = w1; outp = o1; break;
        case 2: in = w2; outp = o2; break;
        case 3: in = w3; outp = o3; break;
        case 4: in = w4; outp = o4; break;
        default: in = w5; outp = o5; break;
    }
    outp[off] = (_Float16)in[off];
}

// ---------------------------------------------------------------- assemble xs/xf
// xs kept f32 (res_ln residual + head); xsh/xfh f16 copies feed the GEMMs.
__global__ void assemble_kernel(
    const float* __restrict__ encx, const float* __restrict__ ency,
    const float* __restrict__ cls, const float* __restrict__ pos,
    const float* __restrict__ maxv, float* __restrict__ xs,
    _Float16* __restrict__ xsh, _Float16* __restrict__ xfh)
{
    int i = blockIdx.x*256 + threadIdx.x;   // < 803840 exact
    int d = i & 127;
    int s = (i >> 7) % NS;
    int b = i / (NS*ND);
    float inv = 1.f / maxv[0];
    float pv = pos[s*ND + d];
    float xv, yv;
    if (s == 0) { xv = cls[d]; yv = cls[d]; }
    else {
        int idx = (b*NP + s - 1)*ND + d;
        xv = encx[idx]*inv; yv = ency[idx]*inv;
    }
    float sx = xv + pv, fx = yv + pv;
    xs[i]  = sx;
    xsh[i] = (_Float16)sx;
    xfh[i] = (_Float16)fx;
}

// ---------------------------------------------------------------- MFMA GEMM (f16 in, f32 acc)
// A and W are f16 at rest: staging is pure h8 loads, no cvt in the hot loop.
// C[M,N] = act(A[M,K] @ W[K,N] + bias[N]); ACT 0=none 1=exact gelu.
// OUTH: 0 -> C float*, 1 -> C _Float16*.
// HW-validated frag conventions (r3/r5/r10): A/B lane row=lane&15, k-run=(lane>>4)*8
// from row-major [row][K] LDS; C/D col=lane&15, row=(lane>>4)*4+reg.
template<int ACT, int OUTH>
__global__ __launch_bounds__(256) void mfma_gemm_kernel(
    const _Float16* __restrict__ A, const _Float16* __restrict__ W,
    const float* __restrict__ bias, void* __restrict__ Cv,
    int M, int N, int K)
{
    __shared__ _Float16 At[128][40];
    __shared__ _Float16 Wt[64][40];    // W^T tile: Wt[n][k]
    const int bm = blockIdx.x * 128, bn = blockIdx.y * 64;
    const int t = threadIdx.x;
    const int lane = t & 63;
    const int wave = t >> 6;
    const int m0 = (wave >> 1) * 64;
    const int n0 = (wave & 1) * 32;
    const int lrow = lane & 15, lhi = lane >> 4;
    f32x4 acc[4][2] = {};

    for (int k0 = 0; k0 < K; k0 += 32) {
        __syncthreads();
        {
            int r = t >> 1, sg = (t & 1) * 16;
            int row = bm + r;
            h8 lo = {}, hi = {};
            if (row < M) {
                const _Float16* src = &A[(size_t)row*K + k0 + sg];
                lo = *(const h8*)&src[0];
                hi = *(const h8*)&src[8];
            }
            *(h8*)&At[r][sg]     = lo;
            *(h8*)&At[r][sg + 8] = hi;
        }
        {
            int kk = t >> 3, nseg = (t & 7) * 8;
            h8 v = *(const h8*)&W[(size_t)(k0 + kk)*N + bn + nseg];
            #pragma unroll
            for (int i = 0; i < 8; i++) Wt[nseg + i][kk] = v[i];
        }
        __syncthreads();
        h8 af[4], bf[2];
        #pragma unroll
        for (int mf = 0; mf < 4; mf++) af[mf] = *(const h8*)&At[m0 + mf*16 + lrow][lhi*8];
        #pragma unroll
        for (int nf = 0; nf < 2; nf++) bf[nf] = *(const h8*)&Wt[n0 + nf*16 + lrow][lhi*8];
        #pragma unroll
        for (int mf = 0; mf < 4; mf++)
            #pragma unroll
            for (int nf = 0; nf < 2; nf++)
                acc[mf][nf] = __builtin_amdgcn_mfma_f32_16x16x32_f16(af[mf], bf[nf], acc[mf][nf], 0, 0, 0);
    }

    #pragma unroll
    for (int nf = 0; nf < 2; nf++) {
        int col = bn + n0 + nf*16 + lrow;
        float bv = bias[col];
        #pragma unroll
        for (int mf = 0; mf < 4; mf++) {
            #pragma unroll
            for (int r = 0; r < 4; r++) {
                int row = bm + m0 + mf*16 + lhi*4 + r;
                if (row < M) {
                    float v = acc[mf][nf][r] + bv;
                    if (ACT == 1) v = 0.5f * v * (1.f + erff(v * 0.70710678118654752f));
                    if (OUTH) ((_Float16*)Cv)[(size_t)row*N + col] = (_Float16)v;
                    else      ((float*)Cv)[(size_t)row*N + col] = v;
                }
            }
        }
    }
}

// ---------------------------------------------------------------- MFMA flash attention
// Q,K,V layout [b][s][h*64+d] f16. Block: 64 q-rows, 4 waves x 16 q-rows.
// Grid (b, h, qt): blocks sharing (b,h) are 64 apart in linear id -> same XCD
// (r10: FETCH 107->9.5 MB/dispatch). O written f16 (feeds Wo GEMM).
__global__ __launch_bounds__(256) void attn_mfma_kernel(
    const _Float16* __restrict__ Q, const _Float16* __restrict__ K,
    const _Float16* __restrict__ V, const int* __restrict__ enc,
    _Float16* __restrict__ O)
{
    __shared__ _Float16 Ks[64][68];      // [k][d], pad 68 -> conflict-free frag reads
    __shared__ _Float16 Vt[64][68];      // [d][k]
    __shared__ _Float16 Ps[4][16][68];   // per-wave P tile [q][k]
    const int b = blockIdx.x, h = blockIdx.y, qt = blockIdx.z;
    const int q0 = qt * 64;
    const int t = threadIdx.x, lane = t & 63, w = t >> 6;
    const int lrow = lane & 15, lhi = lane >> 4;

    h8 qf[2] = {};
    {
        int qrow = q0 + w*16 + lrow;
        if (qrow < NS) {
            const _Float16* src = &Q[(size_t)(b*NS + qrow)*512 + h*64];
            #pragma unroll
            for (int ks = 0; ks < 2; ks++)
                qf[ks] = *(const h8*)&src[ks*32 + lhi*8];
        }
    }

    float m[4], l[4];
    f32x4 acc[4] = {};   // [d-frag]; col=lane&15 -> d, row regs -> q
    #pragma unroll
    for (int r = 0; r < 4; r++) { m[r] = -INFINITY; l[r] = 0.f; }

    for (int kt = 0; kt < 13; kt++) {
        int k0 = kt * 64;
        __syncthreads();
        {
            int r = t >> 2, c0 = (t & 3) * 16;
            int s = k0 + r;
            h8 lo = {}, hi = {};
            if (s < NS) {
                const _Float16* src = &K[(size_t)(b*NS + s)*512 + h*64 + c0];
                lo = *(const h8*)&src[0];
                hi = *(const h8*)&src[8];
            }
            *(h8*)&Ks[r][c0]     = lo;
            *(h8*)&Ks[r][c0 + 8] = hi;
        }
        {
            int r = t >> 2, c0 = (t & 3) * 16;
            int s = k0 + r;
            h8 a = {}, c = {};
            if (s < NS) {
                const _Float16* src = &V[(size_t)(b*NS + s)*512 + h*64 + c0];
                a = *(const h8*)&src[0];
                c = *(const h8*)&src[8];
            }
            #pragma unroll
            for (int i = 0; i < 8; i++) Vt[c0 + i][r] = a[i];
            #pragma unroll
            for (int i = 0; i < 8; i++) Vt[c0 + 8 + i][r] = c[i];
        }
        __syncthreads();

        f32x4 sc[4] = {};
        #pragma unroll
        for (int nf = 0; nf < 4; nf++)
            #pragma unroll
            for (int ks = 0; ks < 2; ks++) {
                h8 bf = *(const h8*)&Ks[nf*16 + lrow][ks*32 + lhi*8];
                sc[nf] = __builtin_amdgcn_mfma_f32_16x16x32_f16(qf[ks], bf, sc[nf], 0, 0, 0);
            }
        #pragma unroll
        for (int nf = 0; nf < 4; nf++) {
            int kk = k0 + nf*16 + lrow;
            bool oob = (kk >= NS);
            float madd = (!oob && enc[b*NS + kk] == 0) ? -1e9f : 0.f;
            #pragma unroll
            for (int r = 0; r < 4; r++) {
                float v = sc[nf][r] * 0.125f + madd;
                sc[nf][r] = oob ? -INFINITY : v;
            }
        }
        float corr[4];
        #pragma unroll
        for (int r = 0; r < 4; r++) {
            float mt = fmaxf(fmaxf(sc[0][r], sc[1][r]), fmaxf(sc[2][r], sc[3][r]));
            mt = fmaxf(mt, __shfl_xor(mt, 1));
            mt = fmaxf(mt, __shfl_xor(mt, 2));
            mt = fmaxf(mt, __shfl_xor(mt, 4));
            mt = fmaxf(mt, __shfl_xor(mt, 8));
            float mn = fmaxf(m[r], mt);
            corr[r] = __expf(m[r] - mn);
            m[r] = mn;
            float ps = 0.f;
            #pragma unroll
            for (int nf = 0; nf < 4; nf++) {
                float p = __expf(sc[nf][r] - mn);
                sc[nf][r] = p;
                ps += p;
            }
            ps += __shfl_xor(ps, 1);
            ps += __shfl_xor(ps, 2);
            ps += __shfl_xor(ps, 4);
            ps += __shfl_xor(ps, 8);
            l[r] = l[r] * corr[r] + ps;
        }
        #pragma unroll
        for (int nf = 0; nf < 4; nf++)
            #pragma unroll
            for (int r = 0; r < 4; r++)
                Ps[w][lhi*4 + r][nf*16 + lrow] = (_Float16)sc[nf][r];
        // wave-local write->read fence (rule #18: waitcnt + sched_barrier)
        asm volatile("s_waitcnt lgkmcnt(0)" ::: "memory");
        __builtin_amdgcn_sched_barrier(0);
        #pragma unroll
        for (int nf = 0; nf < 4; nf++)
            #pragma unroll
            for (int r = 0; r < 4; r++) acc[nf][r] *= corr[r];
        #pragma unroll
        for (int nf = 0; nf < 4; nf++)
            #pragma unroll
            for (int ks = 0; ks < 2; ks++) {
                h8 pf = *(const h8*)&Ps[w][lrow][ks*32 + lhi*8];
                h8 vf = *(const h8*)&Vt[nf*16 + lrow][ks*32 + lhi*8];
                acc[nf] = __builtin_amdgcn_mfma_f32_16x16x32_f16(pf, vf, acc[nf], 0, 0, 0);
            }
    }
    #pragma unroll
    for (int nf = 0; nf < 4; nf++)
        #pragma unroll
        for (int r = 0; r < 4; r++) {
            int row = q0 + w*16 + lhi*4 + r;
            if (row < NS)
                O[(size_t)(b*NS + row)*512 + h*64 + nf*16 + lrow] = (_Float16)(acc[nf][r] / l[r]);
        }
}

// ---------------------------------------------------------------- residual + LN
// Writes f32 (residual stream / head) AND f16 copy (GEMM A-operand).
__global__ __launch_bounds__(256) void res_ln_kernel(
    const float* X, const float* __restrict__ R,
    const float* __restrict__ g, const float* __restrict__ be,
    float* out, _Float16* __restrict__ outh)
{
    int row = blockIdx.x*4 + (threadIdx.x >> 6);
    int lane = threadIdx.x & 63;
    const float* xr = X + (size_t)row*128;
    const float* rr = R + (size_t)row*128;
    float a0 = xr[lane] + rr[lane];
    float a1 = xr[lane+64] + rr[lane+64];
    float s = a0 + a1;
    for (int o = 1; o < 64; o <<= 1) s += __shfl_xor(s, o);
    float mean = s * (1.f/128.f);
    float e0 = a0 - mean, e1 = a1 - mean;
    float vs = e0*e0 + e1*e1;
    for (int o = 1; o < 64; o <<= 1) vs += __shfl_xor(vs, o);
    float rstd = rsqrtf(vs * (1.f/128.f) + 1e-12f);
    float o0 = e0*rstd*g[lane] + be[lane];
    float o1 = e1*rstd*g[lane+64] + be[lane+64];
    out[(size_t)row*128 + lane]       = o0;
    out[(size_t)row*128 + lane + 64]  = o1;
    outh[(size_t)row*128 + lane]      = (_Float16)o0;
    outh[(size_t)row*128 + lane + 64] = (_Float16)o1;
}

// ---------------------------------------------------------------- head
__global__ __launch_bounds__(512) void head_kernel(
    const float* __restrict__ xs, const float* __restrict__ w1,
    const float* __restrict__ w2, float* __restrict__ out)
{
    __shared__ float red[8];
    int b = blockIdx.x, j = threadIdx.x;
    const float* xr = xs + (size_t)(b*NS)*128;
    float acc = 0.f;
    #pragma unroll 8
    for (int c = 0; c < 128; c++) acc += xr[c] * w1[c*512 + j];
    acc = fmaxf(acc, 0.f);
    float sv = acc * w2[j];
    for (int o = 1; o < 64; o <<= 1) sv += __shfl_xor(sv, o);
    if ((j & 63) == 0) red[j >> 6] = sv;
    __syncthreads();
    if (j == 0) {
        float r = 0.f;
        #pragma unroll
        for (int i = 0; i < 8; i++) r += red[i];
        out[b] = r;
    }
}

// ---------------------------------------------------------------- launch
extern "C" void kernel_launch(void* const* d_in, const int* in_sizes, int n_in,
                              void* d_out, int out_size, void* d_ws, size_t ws_size,
                              hipStream_t stream)
{
    const float* conv_w   = (const float*)d_in[0];
    const float* bn_gamma = (const float*)d_in[1];
    const float* bn_beta  = (const float*)d_in[2];
    const float* bn_mean  = (const float*)d_in[3];
    const float* bn_var   = (const float*)d_in[4];
    const float* pos_emb  = (const float*)d_in[5];
    const float* cls_tok  = (const float*)d_in[6];
    const float* Wq = (const float*)d_in[7];  const float* bq = (const float*)d_in[8];
    const float* Wk = (const float*)d_in[9];  const float* bk = (const float*)d_in[10];
    const float* Wv = (const float*)d_in[11]; const float* bv = (const float*)d_in[12];
    const float* Wo = (const float*)d_in[13]; const float* bo = (const float*)d_in[14];
    const float* ln1_g = (const float*)d_in[15]; const float* ln1_b = (const float*)d_in[16];
    const float* fw1 = (const float*)d_in[17]; const float* fb1 = (const float*)d_in[18];
    const float* fw2 = (const float*)d_in[19]; const float* fb2 = (const float*)d_in[20];
    const float* ln2_g = (const float*)d_in[21]; const float* ln2_b = (const float*)d_in[22];
    const float* pw1 = (const float*)d_in[23]; const float* pw2 = (const float*)d_in[24];
    const int*   enc = (const int*)d_in[25];
    const float* x   = (const float*)d_in[26];
    const float* y   = (const float*)d_in[27];
    float* out = (float*)d_out;

    // workspace (all regions 256B-aligned; ~50.5 MB total)
    char* base = (char*)d_ws;
    size_t o = 0;
    auto alloc = [&](size_t bytes) { void* p = base + o; o += bytes; return p; };
    float* maxv     = (float*)alloc(256);
    float* xs       = (float*)alloc(3215360);      // [6280][128] f32
    float* fout     = (float*)alloc(3215360);      // Wo/ffn2 out f32
    float* encx     = (float*)alloc(3211264);      // stem
    float* ency     = (float*)alloc(3211264);
    _Float16* xsh   = (_Float16*)alloc(1607680);   // f16 copies
    _Float16* xfh   = (_Float16*)alloc(1607680);
    _Float16* qh    = (_Float16*)alloc(6430720);   // [6280][512] f16
    _Float16* kh    = (_Float16*)alloc(6430720);
    _Float16* vh    = (_Float16*)alloc(6430720);
    _Float16* ctxh  = (_Float16*)alloc(6430720);
    _Float16* fmidh = (_Float16*)alloc(6430720);
    _Float16* wqh   = (_Float16*)alloc(786432);    // f16 weights, 6 layers each
    _Float16* wkh   = (_Float16*)alloc(786432);
    _Float16* wvh   = (_Float16*)alloc(786432);
    _Float16* woh   = (_Float16*)alloc(786432);
    _Float16* f1h   = (_Float16*)alloc(786432);
    _Float16* f2h   = (_Float16*)alloc(786432);

    hipMemsetAsync(d_ws, 0, 256, stream);   // zero maxval

    wconv_kernel<<<9216, 256, 0, stream>>>(Wq, Wk, Wv, Wo, fw1, fw2,
                                           wqh, wkh, wvh, woh, f1h, f2h);

    dim3 cgrid(49, NB);
    conv_bn_relu_kernel<<<cgrid, 256, 0, stream>>>(x, conv_w, bn_gamma, bn_beta,
        bn_mean, bn_var, encx, (unsigned int*)maxv);
    conv_bn_relu_kernel<<<cgrid, 256, 0, stream>>>(y, conv_w, bn_gamma, bn_beta,
        bn_mean, bn_var, ency, (unsigned int*)maxv);

    assemble_kernel<<<3140, 256, 0, stream>>>(encx, ency, cls_tok, pos_emb, maxv,
                                              xs, xsh, xfh);

    for (int i = 0; i < NL; i++) {
        const size_t wofs = (size_t)i * 128 * 512;
        mfma_gemm_kernel<0,1><<<dim3(50,8), 256, 0, stream>>>(xfh, wqh + wofs, bq + i*512, qh, NM, 512, 128);
        mfma_gemm_kernel<0,1><<<dim3(50,8), 256, 0, stream>>>(xsh, wkh + wofs, bk + i*512, kh, NM, 512, 128);
        mfma_gemm_kernel<0,1><<<dim3(50,8), 256, 0, stream>>>(xsh, wvh + wofs, bv + i*512, vh, NM, 512, 128);
        attn_mfma_kernel<<<dim3(8,8,13), 256, 0, stream>>>(qh, kh, vh, enc, ctxh);
        mfma_gemm_kernel<0,0><<<dim3(50,2), 256, 0, stream>>>(ctxh, woh + wofs, bo + i*128, fout, NM, 128, 512);
        res_ln_kernel<<<1570, 256, 0, stream>>>(xs, fout, ln1_g + i*128, ln1_b + i*128, xs, xsh);
        mfma_gemm_kernel<1,1><<<dim3(50,8), 256, 0, stream>>>(xsh, f1h + wofs, fb1 + i*512, fmidh, NM, 512, 128);
        mfma_gemm_kernel<0,0><<<dim3(50,2), 256, 0, stream>>>(fmidh, f2h + wofs, fb2 + i*128, fout, NM, 128, 512);
        res_ln_kernel<<<1570, 256, 0, stream>>>(xs, fout, ln2_g + i*128, ln2_b + i*128, xs, xsh);
    }

    head_kernel<<<8, 512, 0, stream>>>(xs, pw1, pw2, out);
}